// Round 1
// baseline (755.493 us; speedup 1.0000x reference)
//
#include <hip/hip_runtime.h>

typedef unsigned short u16;
typedef __attribute__((ext_vector_type(4))) float f32x4;
typedef __attribute__((ext_vector_type(8))) short s16x8;   // bf16x8 MFMA fragment
typedef __attribute__((ext_vector_type(4))) unsigned short u16x4;
typedef __attribute__((ext_vector_type(8))) unsigned short u16x8;

#define SCALE_F 0.08838834764831845f

static __device__ __forceinline__ u16 tobf(float f) {
  union { float f; unsigned u; } v; v.f = f;
  return (u16)((v.u + 0x7FFFu + ((v.u >> 16) & 1u)) >> 16);   // RNE
}

static __device__ __forceinline__ void gload16(const void* g, void* l) {
  __builtin_amdgcn_global_load_lds((__attribute__((address_space(1))) void*)g,
                                   (__attribute__((address_space(3))) void*)l,
                                   16, 0, 0);
}

static __device__ __forceinline__ f32x4 mfma16(s16x8 a, s16x8 b, f32x4 c) {
  return __builtin_amdgcn_mfma_f32_16x16x32_bf16(a, b, c, 0, 0, 0);
}

// ---------------- fp32 -> bf16 convert of x and the 4 weight matrices -------
// quads: x [0,2097152), Wq, Wk, Wv (stacked into bW3 [6144][2048]), Wo.
__global__ __launch_bounds__(256) void k_convert(
    const float* __restrict__ x,
    const float* __restrict__ Wq, const float* __restrict__ Wk,
    const float* __restrict__ Wv, const float* __restrict__ Wo,
    u16* __restrict__ bx, u16* __restrict__ bW3, u16* __restrict__ bWo)
{
  int i = blockIdx.x * 256 + threadIdx.x;      // quad index, 6291456 total
  const float* s; u16* d; int o;
  if (i < 2097152)      { s = x;  d = bx;            o = i; }
  else if (i < 3145728) { s = Wq; d = bW3;           o = i - 2097152; }
  else if (i < 4194304) { s = Wk; d = bW3 + 4194304; o = i - 3145728; }
  else if (i < 5242880) { s = Wv; d = bW3 + 8388608; o = i - 4194304; }
  else                  { s = Wo; d = bWo;           o = i - 5242880; }
  f32x4 v = *(const f32x4*)(s + (size_t)o * 4);
  u16x4 r = { tobf(v[0]), tobf(v[1]), tobf(v[2]), tobf(v[3]) };
  *(u16x4*)(d + (size_t)o * 4) = r;
}

// ---------------- past_K: [bh][2048][128] -> d_out K fp32 + ws_K bf16 -------
__global__ __launch_bounds__(256) void k_copyK(
    const float* __restrict__ pK, float* __restrict__ Ko, u16* __restrict__ wsK)
{
  size_t i = (size_t)blockIdx.x * 256 + threadIdx.x;   // quad, 2097152 total
  size_t e = i * 4;
  int dh = (int)(e & 127);
  int p  = (int)((e >> 7) & 2047);
  int bh = (int)(e >> 18);
  size_t o = (((size_t)bh * 4096 + p) << 7) + dh;
  f32x4 v = *(const f32x4*)(pK + e);
  *(f32x4*)(Ko + o) = v;
  u16x4 c = { tobf(v[0]), tobf(v[1]), tobf(v[2]), tobf(v[3]) };
  *(u16x4*)(wsK + o) = c;
}

// ---------------- past_V: passthrough copy + tiled transpose to ws_Vt -------
// grid (ptile=32, bh=32). tile: 64 p x 128 dh.
__global__ __launch_bounds__(256) void k_copyVT(
    const float* __restrict__ pV, float* __restrict__ Vo, u16* __restrict__ wsVt)
{
  __shared__ u16 tile[64 * 136];                 // padded rows (272B): no conflicts
  int bh = blockIdx.y, p0 = blockIdx.x * 64;
  int tid = threadIdx.x;
  const float* src = pV + (((size_t)bh * 2048 + p0) << 7);
  float* dst = Vo + (((size_t)bh * 4096 + p0) << 7);
#pragma unroll
  for (int j = 0; j < 8; ++j) {
    int qd = j * 256 + tid;                      // 0..2047
    int r = qd >> 5, c4 = qd & 31;
    f32x4 v = *(const f32x4*)(src + ((size_t)r << 7) + c4 * 4);
    *(f32x4*)(dst + ((size_t)r << 7) + c4 * 4) = v;
    u16x4 c = { tobf(v[0]), tobf(v[1]), tobf(v[2]), tobf(v[3]) };
    *(u16x4*)&tile[r * 136 + c4 * 4] = c;
  }
  __syncthreads();
  u16* vt = wsVt + ((size_t)bh << 19);
#pragma unroll
  for (int j = 0; j < 4; ++j) {
    int cc = j * 256 + tid;                      // 0..1023
    int dh = cc >> 3, pc = cc & 7;
    u16x8 o;
#pragma unroll
    for (int k2 = 0; k2 < 8; ++k2) o[k2] = tile[(pc * 8 + k2) * 136 + dh];
    *(u16x8*)&vt[(size_t)dh * 4096 + p0 + pc * 8] = o;
  }
}

// ---------------- bf16 GEMM, C = A * B^T (+bias), 128x128 tile, BK=32 -------
// MODE 0: A=x[4096][2048], B=Wqkv[6144][2048]; scatter Q(bf16,*SCALE), K,V.
// MODE 1: A=attn[4096][2048], B=Wo[2048][2048]; out fp32 + bo.
template<int MODE>
__global__ __launch_bounds__(256, 2) void k_gemm(
    const u16* __restrict__ A, const u16* __restrict__ Bw, int K,
    const float* __restrict__ b0, const float* __restrict__ b1,
    const float* __restrict__ b2,
    u16* __restrict__ wsQ, float* __restrict__ Ko, float* __restrict__ Vo,
    u16* __restrict__ wsK, u16* __restrict__ wsVt, float* __restrict__ Co)
{
  __shared__ u16 As[128 * 32];
  __shared__ u16 Bs[128 * 32];
  int tid = threadIdx.x, lane = tid & 63, wave = tid >> 6;
  int wm = wave >> 1, wn = wave & 1;
  int lg = lane & 15, lk = lane >> 4;
  int bm0 = blockIdx.y << 7, bn0 = blockIdx.x << 7;
  const u16* Ab = A + (size_t)bm0 * K;
  const u16* Bb = Bw + (size_t)bn0 * K;

  f32x4 acc[4][4];
#pragma unroll
  for (int mi = 0; mi < 4; ++mi)
#pragma unroll
    for (int ni = 0; ni < 4; ++ni) acc[mi][ni] = {0.f, 0.f, 0.f, 0.f};

  for (int k0 = 0; k0 < K; k0 += 32) {
    __syncthreads();
#pragma unroll
    for (int i = 0; i < 2; ++i) {
      int ci = i * 256 + tid;
      int r = ci >> 2, cc = (ci & 3) << 3;
      gload16(Ab + (size_t)r * K + k0 + cc, &As[ci * 8]);
      gload16(Bb + (size_t)r * K + k0 + cc, &Bs[ci * 8]);
    }
    __syncthreads();
    s16x8 af[4], bfr[4];
#pragma unroll
    for (int mi = 0; mi < 4; ++mi)
      af[mi] = *(const s16x8*)&As[(wm * 64 + mi * 16 + lg) * 32 + lk * 8];
#pragma unroll
    for (int ni = 0; ni < 4; ++ni)
      bfr[ni] = *(const s16x8*)&Bs[(wn * 64 + ni * 16 + lg) * 32 + lk * 8];
#pragma unroll
    for (int mi = 0; mi < 4; ++mi)
#pragma unroll
      for (int ni = 0; ni < 4; ++ni)
        acc[mi][ni] = mfma16(af[mi], bfr[ni], acc[mi][ni]);
  }

  if (MODE == 0) {
    int proj = bn0 >> 11;   // 0=Q 1=K 2=V (uniform per block)
#pragma unroll
    for (int mi = 0; mi < 4; ++mi) {
      int row0 = bm0 + wm * 64 + mi * 16 + lk * 4;  // m = b*2048+s, 4-aligned
      int b = row0 >> 11, s0 = row0 & 2047;
#pragma unroll
      for (int ni = 0; ni < 4; ++ni) {
        int col = bn0 + wn * 64 + ni * 16 + lg;
        int e = col & 2047;
        int h = e >> 7, dh = e & 127;
        float bias = (proj == 0) ? b0[e] : (proj == 1) ? b1[e] : b2[e];
        float v0 = acc[mi][ni][0] + bias, v1 = acc[mi][ni][1] + bias;
        float v2 = acc[mi][ni][2] + bias, v3 = acc[mi][ni][3] + bias;
        if (proj == 0) {
          size_t base = (((size_t)(b * 16 + h) * 2048 + s0) << 7) + dh;
          wsQ[base]       = tobf(v0 * SCALE_F);
          wsQ[base + 128] = tobf(v1 * SCALE_F);
          wsQ[base + 256] = tobf(v2 * SCALE_F);
          wsQ[base + 384] = tobf(v3 * SCALE_F);
        } else {
          size_t base = (((size_t)(b * 16 + h) * 4096 + 2048 + s0) << 7) + dh;
          if (proj == 1) {
            Ko[base] = v0; Ko[base + 128] = v1; Ko[base + 256] = v2; Ko[base + 384] = v3;
            wsK[base] = tobf(v0); wsK[base + 128] = tobf(v1);
            wsK[base + 256] = tobf(v2); wsK[base + 384] = tobf(v3);
          } else {
            Vo[base] = v0; Vo[base + 128] = v1; Vo[base + 256] = v2; Vo[base + 384] = v3;
            size_t tb = ((size_t)(b * 16 + h) * 128 + dh) * 4096 + 2048 + s0;
            u16x4 pk = { tobf(v0), tobf(v1), tobf(v2), tobf(v3) };
            *(u16x4*)&wsVt[tb] = pk;
          }
        }
      }
    }
  } else {
#pragma unroll
    for (int mi = 0; mi < 4; ++mi) {
      int row0 = bm0 + wm * 64 + mi * 16 + lk * 4;
#pragma unroll
      for (int ni = 0; ni < 4; ++ni) {
        int col = bn0 + wn * 64 + ni * 16 + lg;
        float bias = b0[col];
#pragma unroll
        for (int r = 0; r < 4; ++r)
          Co[(size_t)(row0 + r) * 2048 + col] = acc[mi][ni][r] + bias;
      }
    }
  }
}

// ---------------- flash attention: Q[bh][2048][128] (pre-scaled bf16) -------
// K[bh][4096][128] bf16, Vt[bh][128][4096] bf16 -> Oa[4096][2048] bf16.
// grid (qtile=16, bh=32), 4 waves, QBLK=128 (32 q-rows/wave), KVBLK=64.
__global__ __launch_bounds__(256, 2) void k_attn(
    const u16* __restrict__ Qg, const u16* __restrict__ Kg,
    const u16* __restrict__ Vtg, u16* __restrict__ Oa)
{
  __shared__ u16 Ks[64 * 128];    // XOR-swizzled rows (256B)
  __shared__ u16 Vs[128 * 64];    // XOR-swizzled rows (128B)
  __shared__ u16 Ps[4][32 * 72];  // per-wave P, padded stride 144B

  int tid = threadIdx.x, lane = tid & 63, wave = tid >> 6;
  int lg = lane & 15, lk = lane >> 4;
  int bh = blockIdx.y, qt = blockIdx.x;
  int q0 = (qt << 7) + (wave << 5);

  const u16* Qb = Qg + ((size_t)bh * 2048 + q0) * 128;
  s16x8 qf[2][4];
#pragma unroll
  for (int mi = 0; mi < 2; ++mi)
#pragma unroll
    for (int kk = 0; kk < 4; ++kk)
      qf[mi][kk] = *(const s16x8*)&Qb[(size_t)(mi * 16 + lg) * 128 + kk * 32 + lk * 8];

  const char* Kbh = (const char*)(Kg + ((size_t)bh << 19));
  const char* Vbh = (const char*)(Vtg + ((size_t)bh << 19));

  f32x4 accO[2][8];
#pragma unroll
  for (int mi = 0; mi < 2; ++mi)
#pragma unroll
    for (int di = 0; di < 8; ++di) accO[mi][di] = {0.f, 0.f, 0.f, 0.f};
  float mrow[2][4], lrow[2][4];
#pragma unroll
  for (int mi = 0; mi < 2; ++mi)
#pragma unroll
    for (int r = 0; r < 4; ++r) { mrow[mi][r] = -1e30f; lrow[mi][r] = 0.f; }

  u16* Pw = &Ps[wave][0];

  for (int t0 = 0; t0 < 4096; t0 += 64) {
    __syncthreads();
    // stage K tile [64][128]: pre-swizzled global source, linear LDS dest
#pragma unroll
    for (int i = 0; i < 4; ++i) {
      int ci = i * 256 + tid;
      int r = ci >> 4, cb = (ci & 15) << 4;
      gload16(Kbh + (size_t)(t0 + r) * 256 + (cb ^ ((r & 7) << 4)),
              (char*)Ks + ci * 16);
    }
    // stage Vt tile [128][64]
#pragma unroll
    for (int i = 0; i < 4; ++i) {
      int ci = i * 256 + tid;
      int d = ci >> 3, cb = (ci & 7) << 4;
      gload16(Vbh + (size_t)d * 8192 + t0 * 2 + (cb ^ ((d & 7) << 4)),
              (char*)Vs + ci * 16);
    }
    __syncthreads();

    // S = Q K^T  (D[q][kv])
    f32x4 sa[2][4];
#pragma unroll
    for (int mi = 0; mi < 2; ++mi)
#pragma unroll
      for (int ni = 0; ni < 4; ++ni) sa[mi][ni] = {0.f, 0.f, 0.f, 0.f};
#pragma unroll
    for (int ni = 0; ni < 4; ++ni) {
      int row = ni * 16 + lg;
#pragma unroll
      for (int kk = 0; kk < 4; ++kk) {
        int kb = (kk * 32 + lk * 8) << 1;
        s16x8 kf = *(const s16x8*)((const char*)Ks + row * 256 + (kb ^ ((row & 7) << 4)));
        sa[0][ni] = mfma16(qf[0][kk], kf, sa[0][ni]);
        sa[1][ni] = mfma16(qf[1][kk], kf, sa[1][ni]);
      }
    }

    // online softmax (rows q = mi*16 + lk*4 + r, cols kv = ni*16 + lg)
    float fs[2][4];
#pragma unroll
    for (int mi = 0; mi < 2; ++mi)
#pragma unroll
      for (int r = 0; r < 4; ++r) {
        float v = fmaxf(fmaxf(sa[mi][0][r], sa[mi][1][r]),
                        fmaxf(sa[mi][2][r], sa[mi][3][r]));
        v = fmaxf(v, __shfl_xor(v, 1, 64));
        v = fmaxf(v, __shfl_xor(v, 2, 64));
        v = fmaxf(v, __shfl_xor(v, 4, 64));
        v = fmaxf(v, __shfl_xor(v, 8, 64));
        float nm = fmaxf(mrow[mi][r], v);
        fs[mi][r] = __expf(mrow[mi][r] - nm);
        mrow[mi][r] = nm;
      }
#pragma unroll
    for (int mi = 0; mi < 2; ++mi)
#pragma unroll
      for (int r = 0; r < 4; ++r) {
        float sum = 0.f;
#pragma unroll
        for (int ni = 0; ni < 4; ++ni) {
          float p = __expf(sa[mi][ni][r] - mrow[mi][r]);
          sa[mi][ni][r] = p;
          sum += p;
        }
        sum += __shfl_xor(sum, 1, 64);
        sum += __shfl_xor(sum, 2, 64);
        sum += __shfl_xor(sum, 4, 64);
        sum += __shfl_xor(sum, 8, 64);
        lrow[mi][r] = lrow[mi][r] * fs[mi][r] + sum;
      }
#pragma unroll
    for (int mi = 0; mi < 2; ++mi)
#pragma unroll
      for (int di = 0; di < 8; ++di)
#pragma unroll
        for (int r = 0; r < 4; ++r) accO[mi][di][r] *= fs[mi][r];

    // P -> LDS (bf16), transposing C-layout to A-fragment layout
#pragma unroll
    for (int mi = 0; mi < 2; ++mi)
#pragma unroll
      for (int ni = 0; ni < 4; ++ni)
#pragma unroll
        for (int r = 0; r < 4; ++r)
          Pw[(mi * 16 + lk * 4 + r) * 72 + ni * 16 + lg] = tobf(sa[mi][ni][r]);
    asm volatile("s_waitcnt lgkmcnt(0)" ::: "memory");
    __builtin_amdgcn_sched_barrier(0);

    // O += P @ V   (A=P[q][kv], B=Vt[d][kv])
#pragma unroll
    for (int ks = 0; ks < 2; ++ks) {
      s16x8 pf0 = *(const s16x8*)&Pw[lg * 72 + ks * 32 + lk * 8];
      s16x8 pf1 = *(const s16x8*)&Pw[(16 + lg) * 72 + ks * 32 + lk * 8];
      int kb = (ks * 32 + lk * 8) << 1;
#pragma unroll
      for (int di = 0; di < 8; ++di) {
        int dr = di * 16 + lg;
        s16x8 vf = *(const s16x8*)((const char*)Vs + dr * 128 + (kb ^ ((dr & 7) << 4)));
        accO[0][di] = mfma16(pf0, vf, accO[0][di]);
        accO[1][di] = mfma16(pf1, vf, accO[1][di]);
      }
    }
  }

  // epilogue: O /= l, write bf16 [b*2048+s][h*128+d]
  int b = bh >> 4, h = bh & 15;
#pragma unroll
  for (int mi = 0; mi < 2; ++mi) {
    float inv[4];
#pragma unroll
    for (int r = 0; r < 4; ++r) inv[r] = 1.f / lrow[mi][r];
#pragma unroll
    for (int di = 0; di < 8; ++di)
#pragma unroll
      for (int r = 0; r < 4; ++r) {
        int s = q0 + mi * 16 + lk * 4 + r;
        int d = h * 128 + di * 16 + lg;
        Oa[(size_t)(b * 2048 + s) * 2048 + d] = tobf(accO[mi][di][r] * inv[r]);
      }
  }
}

// ---------------------------------------------------------------------------
extern "C" void kernel_launch(void* const* d_in, const int* in_sizes, int n_in,
                              void* d_out, int out_size, void* d_ws, size_t ws_size,
                              hipStream_t stream) {
  const float* x  = (const float*)d_in[0];
  const float* pK = (const float*)d_in[1];
  const float* pV = (const float*)d_in[2];
  const float* Wq = (const float*)d_in[3];
  const float* bq = (const float*)d_in[4];
  const float* Wk = (const float*)d_in[5];
  const float* bk = (const float*)d_in[6];
  const float* Wv = (const float*)d_in[7];
  const float* bv = (const float*)d_in[8];
  const float* Wo = (const float*)d_in[9];
  const float* bo = (const float*)d_in[10];

  float* out  = (float*)d_out;          // [4096][2048]
  float* Kout = out + 8388608;          // [32][4096][128]
  float* Vout = Kout + 16777216;        // [32][4096][128]

  if (ws_size < 134217728) return;      // need 128 MiB scratch
  char* w = (char*)d_ws;
  u16* ws_x    = (u16*)(w);                    // [4096][2048] bf16 (aliased by ws_attn)
  u16* ws_Wqkv = (u16*)(w + 16777216);         // [6144][2048] bf16
  u16* ws_Wo   = (u16*)(w + 41943040);         // [2048][2048] bf16
  u16* ws_Q    = (u16*)(w + 50331648);         // [32][2048][128] bf16, pre-scaled
  u16* ws_K    = (u16*)(w + 67108864);         // [32][4096][128] bf16
  u16* ws_Vt   = (u16*)(w + 100663296);        // [32][128][4096] bf16
  u16* ws_attn = ws_x;                         // [4096][2048] bf16 (x dead after GEMM1)

  k_convert<<<24576, 256, 0, stream>>>(x, Wq, Wk, Wv, Wo, ws_x, ws_Wqkv, ws_Wo);
  k_copyK<<<8192, 256, 0, stream>>>(pK, Kout, ws_K);
  k_copyVT<<<dim3(32, 32), 256, 0, stream>>>(pV, Vout, ws_Vt);
  k_gemm<0><<<dim3(48, 32), 256, 0, stream>>>(ws_x, ws_Wqkv, 2048, bq, bk, bv,
                                              ws_Q, Kout, Vout, ws_K, ws_Vt, nullptr);
  k_attn<<<dim3(16, 32), 256, 0, stream>>>(ws_Q, ws_K, ws_Vt, ws_attn);
  k_gemm<1><<<dim3(16, 32), 256, 0, stream>>>(ws_attn, ws_Wo, 2048, bo, nullptr, nullptr,
                                              nullptr, nullptr, nullptr, nullptr, nullptr, out);
}